// Round 5
// baseline (195.730 us; speedup 1.0000x reference)
//
#include <hip/hip_runtime.h>

#define NN 4096
#define TT 365
#define CC 32
#define RPB 2                  // rows per block
#define BLOCK 256              // 4 waves
#define GRID (NN / RPB)        // 2048  -> 8192 waves = 8/SIMD
#define F4_PER_ROW (TT * CC / 4)   // 2920
#define NBANK 8

// Workspace layout (doubles):
// [0 .. 8*TT)          cls banks: bank b, t -> ws[b*TT + t]
// [8TT .. 8TT+8)       earliness banks
// [8TT+8 .. +CC)       A[c]
// [.. +CC)             B[c]
// [.. +CC)             D[c]
// then one uint32 completion counter at byte offset WS_DOUBLES*8
#define CLS0   0
#define EARL0  (NBANK * TT)
#define MOM0   (EARL0 + NBANK)
#define WS_DOUBLES (MOM0 + 3 * CC)
#define WS_BYTES (WS_DOUBLES * 8 + 8)

__global__ __launch_bounds__(BLOCK) void stp_main(
    const float* __restrict__ logp,   // (N,T,C)
    const float* __restrict__ tl,     // (N,T) -- only column 0 read
    const int*  __restrict__ yt,      // (N,T) -- only column 0 read
    double* __restrict__ ws,
    unsigned int* __restrict__ done_ctr,
    float* __restrict__ out)
{
    __shared__ float  s_cls[8][TT + 7];   // [chunk j][t]; bijective stores
    __shared__ double s_red[BLOCK / 64];
    __shared__ bool   s_last;

    const int tid = threadIdx.x;
    const int n0  = blockIdx.x * RPB;

    int lab[RPB], j0[RPB], comp[RPB];
    float tff[RPB];
    const float4* row4[RPB];
    #pragma unroll
    for (int r = 0; r < RPB; ++r) {
        const size_t rb = (size_t)(n0 + r) * TT;
        lab[r]  = yt[rb];
        tff[r]  = tl[rb];              // tl[n,0] = t_final (exact small int)
        j0[r]   = lab[r] >> 2;
        comp[r] = lab[r] & 3;
        row4[r] = (const float4*)(logp + rb * CC);
    }

    double earl = 0.0;
    const float invT = 1.0f / 365.0f;

    #pragma unroll 2
    for (int i = tid; i < F4_PER_ROW; i += BLOCK) {
        float4 v[RPB];
        #pragma unroll
        for (int r = 0; r < RPB; ++r) v[r] = row4[r][i];

        const int   j  = i & 7;
        const int   t  = i >> 3;
        const float tF = (float)t;
        const float wt = 1.0f - tF * invT;

        float acc = 0.0f;
        #pragma unroll
        for (int r = 0; r < RPB; ++r) {
            if (j == j0[r]) {
                const int   c  = comp[r];
                const float lp = c == 0 ? v[r].x : c == 1 ? v[r].y
                               : c == 2 ? v[r].z : v[r].w;
                acc -= lp;
                const float pc  = expf(lp);
                const float tlv = fmaxf(tff[r] - tF, 0.0f);
                earl += (double)(pc * wt * (1.0f - tlv * invT));
                if (tF == tff[r]) {
                    const double e   = (double)pc;
                    const double tfd = (double)tF;
                    atomicAdd(&ws[MOM0 + lab[r]],          e);
                    atomicAdd(&ws[MOM0 + CC + lab[r]],     e * tfd);
                    atomicAdd(&ws[MOM0 + 2 * CC + lab[r]], e * tfd * tfd);
                }
            }
        }
        s_cls[j][t] = acc;               // unique (j,t) per thread, no init
    }

    for (int off = 32; off > 0; off >>= 1)
        earl += __shfl_down(earl, off, 64);
    if ((tid & 63) == 0) s_red[tid >> 6] = earl;
    __syncthreads();

    const int bank = blockIdx.x & (NBANK - 1);
    for (int i = tid; i < TT; i += BLOCK) {
        float s = 0.0f;
        #pragma unroll
        for (int jj = 0; jj < 8; ++jj) s += s_cls[jj][i];
        atomicAdd(&ws[CLS0 + bank * TT + i], (double)s);
    }
    if (tid == 0) {
        double s = 0.0;
        #pragma unroll
        for (int w = 0; w < BLOCK / 64; ++w) s += s_red[w];
        atomicAdd(&ws[EARL0 + bank], s);
    }

    // ---- last block finalizes (saves a kernel launch) ----
    __threadfence();
    __syncthreads();
    if (tid == 0)
        s_last = (atomicAdd(done_ctr, 1u) == GRID - 1);
    __syncthreads();
    if (!s_last) return;
    __threadfence();  // make all other blocks' atomics visible to our reads

    __shared__ double s_scalar;
    if (tid == 0) {
        double p = 0.0;
        #pragma unroll
        for (int c = 0; c < CC; ++c) {
            const double A = ws[MOM0 + c];
            const double B = ws[MOM0 + CC + c];
            const double D = ws[MOM0 + 2 * CC + c];
            p += A * D - B * B;
        }
        p /= (365.0 * 365.0);
        double e = 0.0;
        #pragma unroll
        for (int b = 0; b < NBANK; ++b) e += ws[EARL0 + b];
        e /= (double)NN;
        s_scalar = (1.0 / 3.0) * (e + p);
    }
    __syncthreads();
    for (int i = tid; i < TT; i += BLOCK) {
        double cls = 0.0;
        #pragma unroll
        for (int b = 0; b < NBANK; ++b) cls += ws[CLS0 + b * TT + i];
        cls /= (double)NN;
        out[i] = (float)((1.0 / 3.0) * cls - s_scalar);
    }
}

extern "C" void kernel_launch(void* const* d_in, const int* in_sizes, int n_in,
                              void* d_out, int out_size, void* d_ws, size_t ws_size,
                              hipStream_t stream)
{
    const float* logp = (const float*)d_in[0];
    const float* tl   = (const float*)d_in[1];
    const int*   yt   = (const int*)d_in[2];
    float* out = (float*)d_out;
    double* ws = (double*)d_ws;
    unsigned int* ctr = (unsigned int*)((char*)d_ws + WS_DOUBLES * 8);

    hipMemsetAsync(d_ws, 0, WS_BYTES, stream);
    stp_main<<<GRID, BLOCK, 0, stream>>>(logp, tl, yt, ws, ctr, out);
}

// Round 6
// 70.852 us; speedup vs baseline: 2.7625x; 2.7625x over previous
//
#include <hip/hip_runtime.h>

#define NN 4096
#define TT 365
#define CC 32
#define RPB 8                      // rows per block
#define BLOCK 512                  // 8 waves; grid 512 -> 4 waves/SIMD
#define GRID (NN / RPB)            // 512
#define F4_PER_ROW (TT * CC / 4)   // 2920
#define CLS_STRIDE 368             // padded TT (LDS rows and ws cls stride)

// ws layout (doubles), ALL plain-stored every call (no memset needed):
// [0 .. GRID*CLS_STRIDE)  per-block cls partials: ws[b*CLS_STRIDE + t]
// [E0 .. E0+GRID)         per-block earliness partials
// [ROWE0 .. ROWE0+NN)     per-row e = exp(logp[n, tf, label])
#define E0    (GRID * CLS_STRIDE)
#define ROWE0 (E0 + GRID)
#define WS_DOUBLES (ROWE0 + NN)

__global__ __launch_bounds__(BLOCK) void stp_main(
    const float* __restrict__ logp,   // (N,T,C)
    const float* __restrict__ tl,     // (N,T) -- only column 0 read
    const int*  __restrict__ yt,      // (N,T) -- only column 0 read
    double* __restrict__ ws)
{
    __shared__ float  s_cls[8][CLS_STRIDE];   // [chunk j][t]; bijective stores
    __shared__ double s_red[BLOCK / 64];

    const int tid = threadIdx.x;
    const int n0  = blockIdx.x * RPB;

    int   lab[RPB], j0[RPB], comp[RPB];
    float tff[RPB];
    const float* rowp[RPB];
    #pragma unroll
    for (int r = 0; r < RPB; ++r) {
        const size_t rb = (size_t)(n0 + r) * TT;
        lab[r]  = yt[rb];
        tff[r]  = tl[rb];              // tl[n,0] = lengths-1 = t_final (exact)
        j0[r]   = lab[r] >> 2;         // owning float4 chunk within 32-float cell
        comp[r] = lab[r] & 3;          // component within that float4
        rowp[r] = logp + rb * CC;
    }

    float earl = 0.0f;                 // f32 partial (<=46 terms, each <=1)
    const float invT = 1.0f / 365.0f;

    for (int i = tid; i < F4_PER_ROW; i += BLOCK) {
        // 8 independent coalesced loads, all in flight
        float4 v[RPB];
        #pragma unroll
        for (int r = 0; r < RPB; ++r)
            v[r] = *(const float4*)(rowp[r] + (size_t)i * 4);

        const int   j  = i & 7;
        const int   t  = i >> 3;
        const float tF = (float)t;
        const float wt = 1.0f - tF * invT;

        float acc = 0.0f;              // sum over matching rows of -lp
        #pragma unroll
        for (int r = 0; r < RPB; ++r) {
            if (j == j0[r]) {
                const int   c  = comp[r];
                const float lp = c == 0 ? v[r].x : c == 1 ? v[r].y
                               : c == 2 ? v[r].z : v[r].w;
                acc -= lp;
                const float pc  = __expf(lp);
                const float tlv = fmaxf(tff[r] - tF, 0.0f);
                earl += pc * wt * (1.0f - tlv * invT);
            }
        }
        s_cls[j][t] = acc;             // unique (j,t) per thread, no init needed
    }

    // per-row stopping-time e (one lane per row; line is L2/L3-hot)
    if (tid < RPB) {
        const size_t rb = (size_t)(n0 + tid) * TT;
        const int lb = yt[rb];
        const int tf = (int)tl[rb];
        const float lph = logp[rb * CC + (size_t)tf * CC + lb];
        ws[ROWE0 + n0 + tid] = (double)__expf(lph);
    }

    // earliness block partial: wave f64 shuffle-reduce -> plain store
    double ed = (double)earl;
    for (int off = 32; off > 0; off >>= 1)
        ed += __shfl_down(ed, off, 64);
    if ((tid & 63) == 0) s_red[tid >> 6] = ed;
    __syncthreads();
    if (tid == 0) {
        double s = 0.0;
        #pragma unroll
        for (int w = 0; w < BLOCK / 64; ++w) s += s_red[w];
        ws[E0 + blockIdx.x] = s;
    }

    // cls block partial: sum 8 chunk slices, plain coalesced f64 store
    if (tid < TT) {
        float s = 0.0f;
        #pragma unroll
        for (int jj = 0; jj < 8; ++jj) s += s_cls[jj][tid];
        ws[(size_t)blockIdx.x * CLS_STRIDE + tid] = (double)s;
    }
}

__global__ __launch_bounds__(1024) void stp_finalize(
    const double* __restrict__ ws,
    const float* __restrict__ tl,
    const int*  __restrict__ yt,
    float* __restrict__ out)
{
    __shared__ double sA[CC], sB[CC], sD[CC];
    __shared__ double s_earl[8];
    __shared__ double s_scalar;

    const int tid = threadIdx.x;
    if (tid < CC) { sA[tid] = 0.0; sB[tid] = 0.0; sD[tid] = 0.0; }
    __syncthreads();

    // Section A (waves 0-7): cls[t] = sum over 512 block partials
    double cls_t = 0.0;
    if (tid < TT) {
        double c0 = 0.0, c1 = 0.0, c2 = 0.0, c3 = 0.0;
        for (int b = 0; b < GRID; b += 4) {
            c0 += ws[(size_t)(b)     * CLS_STRIDE + tid];
            c1 += ws[(size_t)(b + 1) * CLS_STRIDE + tid];
            c2 += ws[(size_t)(b + 2) * CLS_STRIDE + tid];
            c3 += ws[(size_t)(b + 3) * CLS_STRIDE + tid];
        }
        cls_t = (c0 + c1) + (c2 + c3);
    }

    // Section B (waves 8-15): earliness total + class moments
    if (tid >= 512) {
        const int u = tid - 512;
        double e = ws[E0 + u];
        for (int off = 32; off > 0; off >>= 1)
            e += __shfl_down(e, off, 64);
        if ((u & 63) == 0) s_earl[u >> 6] = e;

        #pragma unroll
        for (int k = 0; k < NN / 512; ++k) {
            const int n = u + k * 512;
            const size_t rb = (size_t)n * TT;
            const double ev  = ws[ROWE0 + n];
            const int    lb  = yt[rb];
            const double tfd = (double)tl[rb];
            atomicAdd(&sA[lb], ev);
            atomicAdd(&sB[lb], ev * tfd);
            atomicAdd(&sD[lb], ev * tfd * tfd);
        }
    }
    __syncthreads();

    if (tid == 0) {
        double p = 0.0;
        #pragma unroll
        for (int c = 0; c < CC; ++c)
            p += sA[c] * sD[c] - sB[c] * sB[c];
        p /= (365.0 * 365.0);
        double e = 0.0;
        #pragma unroll
        for (int w = 0; w < 8; ++w) e += s_earl[w];
        e /= (double)NN;
        s_scalar = (1.0 / 3.0) * (e + p);
    }
    __syncthreads();

    if (tid < TT)
        out[tid] = (float)((1.0 / 3.0) * (cls_t / (double)NN) - s_scalar);
}

extern "C" void kernel_launch(void* const* d_in, const int* in_sizes, int n_in,
                              void* d_out, int out_size, void* d_ws, size_t ws_size,
                              hipStream_t stream)
{
    const float* logp = (const float*)d_in[0];
    const float* tl   = (const float*)d_in[1];
    const int*   yt   = (const int*)d_in[2];
    float* out = (float*)d_out;
    double* ws = (double*)d_ws;

    stp_main<<<GRID, BLOCK, 0, stream>>>(logp, tl, yt, ws);
    stp_finalize<<<1, 1024, 0, stream>>>(ws, tl, yt, out);
}

// Round 7
// 45.822 us; speedup vs baseline: 4.2716x; 1.5462x over previous
//
#include <hip/hip_runtime.h>

#define NN 4096
#define TT 365
#define CC 32
#define RPB 4                      // rows per block
#define BLOCK 512                  // 8 waves
#define GRID (NN / RPB)            // 1024 blocks -> 4 blocks/CU, 32 waves/CU
#define F4_PER_ROW (TT * CC / 4)   // 2920
#define LDS_PAD 369                // 369%32=17 -> spreads j-chunks across banks

// ws layout (doubles), every location plain-stored each call (no memset):
// [0 .. TT*GRID)       cls partials TRANSPOSED: ws[t*GRID + b]
// [E0 .. E0+GRID)      per-block earliness partials
// [ROW0 .. ROW0+4*NN)  per-row quads: e, e*tf, e*tf^2, (double)label
// [SC]                 scalar (written by k2, read by k3)
#define E0   (TT * GRID)
#define ROW0 (E0 + GRID)
#define SC   (ROW0 + 4 * NN)

__global__ __launch_bounds__(BLOCK, 8) void stp_main(
    const float* __restrict__ logp,   // (N,T,C)
    const float* __restrict__ tl,     // (N,T) -- only column 0 read
    const int*  __restrict__ yt,      // (N,T) -- only column 0 read
    double* __restrict__ ws)
{
    __shared__ float  s_cls[8][LDS_PAD];   // [chunk j][t]; bijective stores
    __shared__ double s_red[BLOCK / 64];

    const int tid = threadIdx.x;
    const int n0  = blockIdx.x * RPB;

    int   lab[RPB], j0[RPB], comp[RPB];
    float tff[RPB];
    const float4* row4[RPB];
    #pragma unroll
    for (int r = 0; r < RPB; ++r) {
        const size_t rb = (size_t)(n0 + r) * TT;
        lab[r]  = yt[rb];              // block-uniform -> scalar regs
        tff[r]  = tl[rb];              // tl[n,0] = lengths-1 = t_final (exact)
        j0[r]   = lab[r] >> 2;
        comp[r] = lab[r] & 3;
        row4[r] = (const float4*)(logp + rb * CC);
    }

    float earl = 0.0f;                 // few owner terms per thread -> f32 ok
    const float invT = 1.0f / 365.0f;

    for (int i = tid; i < F4_PER_ROW; i += BLOCK) {
        float4 v[RPB];                 // RPB independent loads in flight
        #pragma unroll
        for (int r = 0; r < RPB; ++r) v[r] = row4[r][i];

        const int   j  = i & 7;
        const int   t  = i >> 3;
        const float tF = (float)t;
        const float wt = 1.0f - tF * invT;

        float acc = 0.0f;
        #pragma unroll
        for (int r = 0; r < RPB; ++r) {
            if (j == j0[r]) {
                const int   c  = comp[r];
                const float lp = c == 0 ? v[r].x : c == 1 ? v[r].y
                               : c == 2 ? v[r].z : v[r].w;
                acc -= lp;
                const float pc  = __expf(lp);
                const float tlv = fmaxf(tff[r] - tF, 0.0f);
                earl += pc * wt * (1.0f - tlv * invT);
            }
        }
        s_cls[j][t] = acc;             // unique (j,t) per thread; all written
    }

    // per-row stopping-time quad (line is L2-hot from the stream)
    if (tid < RPB) {
        const int n = n0 + tid;
        const size_t rb = (size_t)n * TT;
        const int lb = yt[rb];
        const int tf = (int)tl[rb];
        const double e   = (double)__expf(logp[rb * CC + (size_t)tf * CC + lb]);
        const double tfd = (double)tf;
        ws[ROW0 + 4 * n + 0] = e;
        ws[ROW0 + 4 * n + 1] = e * tfd;
        ws[ROW0 + 4 * n + 2] = e * tfd * tfd;
        ws[ROW0 + 4 * n + 3] = (double)lb;
    }

    // earliness block partial: f64 wave reduce -> plain store
    double ed = (double)earl;
    for (int off = 32; off > 0; off >>= 1)
        ed += __shfl_down(ed, off, 64);
    if ((tid & 63) == 0) s_red[tid >> 6] = ed;
    __syncthreads();
    if (tid == 0) {
        double s = 0.0;
        #pragma unroll
        for (int w = 0; w < BLOCK / 64; ++w) s += s_red[w];
        ws[E0 + blockIdx.x] = s;
    }

    // cls block partial -> transposed store (contiguous reads in k3)
    if (tid < TT) {
        float s = 0.0f;
        #pragma unroll
        for (int jj = 0; jj < 8; ++jj) s += s_cls[jj][tid];
        ws[(size_t)tid * GRID + blockIdx.x] = (double)s;
    }
}

__global__ __launch_bounds__(512) void stp_scalar(
    double* __restrict__ ws)
{
    __shared__ double sA[CC], sB[CC], sD[CC];
    __shared__ double s_red[8];
    const int tid = threadIdx.x;

    if (tid < CC) { sA[tid] = 0.0; sB[tid] = 0.0; sD[tid] = 0.0; }
    __syncthreads();

    // earliness: 1024 partials
    double e = ws[E0 + tid] + ws[E0 + 512 + tid];
    for (int off = 32; off > 0; off >>= 1)
        e += __shfl_down(e, off, 64);
    if ((tid & 63) == 0) s_red[tid >> 6] = e;

    // class moments from per-row quads (coalesced 32B reads)
    #pragma unroll
    for (int k = 0; k < NN / 512; ++k) {
        const int n = tid + k * 512;
        const double ev = ws[ROW0 + 4 * n + 0];
        const double b  = ws[ROW0 + 4 * n + 1];
        const double d  = ws[ROW0 + 4 * n + 2];
        const int    lb = (int)ws[ROW0 + 4 * n + 3];
        atomicAdd(&sA[lb], ev);
        atomicAdd(&sB[lb], b);
        atomicAdd(&sD[lb], d);
    }
    __syncthreads();

    if (tid == 0) {
        double p = 0.0;
        #pragma unroll
        for (int c = 0; c < CC; ++c)
            p += sA[c] * sD[c] - sB[c] * sB[c];
        p /= (365.0 * 365.0);
        double et = 0.0;
        #pragma unroll
        for (int w = 0; w < 8; ++w) et += s_red[w];
        et /= (double)NN;
        ws[SC] = (1.0 / 3.0) * (et + p);
    }
}

__global__ __launch_bounds__(256) void stp_out(
    const double* __restrict__ ws, float* __restrict__ out)
{
    __shared__ double s_red[4];
    const int t   = blockIdx.x;
    const int tid = threadIdx.x;

    const double* p = ws + (size_t)t * GRID;
    double s = 0.0;
    #pragma unroll
    for (int k = 0; k < GRID / 256; ++k) s += p[tid + k * 256];
    for (int off = 32; off > 0; off >>= 1)
        s += __shfl_down(s, off, 64);
    if ((tid & 63) == 0) s_red[tid >> 6] = s;
    __syncthreads();
    if (tid == 0) {
        double cls = s_red[0] + s_red[1] + s_red[2] + s_red[3];
        out[t] = (float)((1.0 / 3.0) * (cls / (double)NN) - ws[SC]);
    }
}

extern "C" void kernel_launch(void* const* d_in, const int* in_sizes, int n_in,
                              void* d_out, int out_size, void* d_ws, size_t ws_size,
                              hipStream_t stream)
{
    const float* logp = (const float*)d_in[0];
    const float* tl   = (const float*)d_in[1];
    const int*   yt   = (const int*)d_in[2];
    float* out = (float*)d_out;
    double* ws = (double*)d_ws;

    stp_main<<<GRID, BLOCK, 0, stream>>>(logp, tl, yt, ws);
    stp_scalar<<<1, 512, 0, stream>>>(ws);
    stp_out<<<TT, 256, 0, stream>>>(ws, out);
}

// Round 8
// 44.494 us; speedup vs baseline: 4.3990x; 1.0298x over previous
//
#include <hip/hip_runtime.h>

#define NN 4096
#define TT 365
#define CC 32
#define RPB 4                      // rows per block
#define BLOCK 512                  // 8 waves
#define GRID (NN / RPB)            // 1024 blocks -> 32 waves/CU (8/SIMD)
#define F4_PER_ROW (TT * CC / 4)   // 2920
#define NITER 6                    // ceil(2920/512); tail lanes: tid < 360
#define TAILN (F4_PER_ROW - (NITER - 1) * BLOCK)   // 360
#define LDS_PAD 369

// ws layout (doubles), every location plain-stored each call (no memset):
// [0 .. TT*GRID)       cls partials TRANSPOSED: ws[t*GRID + b]
// [E0 .. E0+GRID)      per-block earliness partials
// [ROW0 .. ROW0+4*NN)  per-row quads: e, e*tf, e*tf^2, (double)label
// [SC]                 scalar (written by k2, read by k3)
#define E0   (TT * GRID)
#define ROW0 (E0 + GRID)
#define SC   (ROW0 + 4 * NN)

__global__ __launch_bounds__(BLOCK, 8) void stp_main(
    const float* __restrict__ logp,   // (N,T,C)
    const float* __restrict__ tl,     // (N,T) -- only column 0 read
    const int*  __restrict__ yt,      // (N,T) -- only column 0 read
    double* __restrict__ ws)
{
    __shared__ float  s_cls[8][LDS_PAD];   // [chunk j][t]; bijective stores
    __shared__ double s_red[BLOCK / 64];

    const int tid = threadIdx.x;
    const int n0  = blockIdx.x * RPB;

    int   lab[RPB], j0[RPB], comp[RPB];
    float tff[RPB];
    const float4* row4[RPB];
    #pragma unroll
    for (int r = 0; r < RPB; ++r) {
        const size_t rb = (size_t)(n0 + r) * TT;
        lab[r]  = yt[rb];              // block-uniform -> scalar regs
        tff[r]  = tl[rb];              // tl[n,0] = lengths-1 = t_final (exact)
        j0[r]   = lab[r] >> 2;
        comp[r] = lab[r] & 3;
        row4[r] = (const float4*)(logp + rb * CC);
    }

    float earl = 0.0f;
    const float invT = 1.0f / 365.0f;
    const int   j    = tid & 7;        // fixed chunk index per thread

    // -------- software-pipelined, fully-unrolled hot loop --------
    float4 buf[2][RPB];
    #pragma unroll
    for (int r = 0; r < RPB; ++r) buf[0][r] = row4[r][tid];

    #pragma unroll
    for (int k = 0; k < NITER; ++k) {
        const int cur = k & 1;
        // prefetch iteration k+1 while processing k
        if (k + 1 < NITER) {
            if (k + 1 < NITER - 1 || tid < TAILN) {
                const int inx = tid + (k + 1) * BLOCK;
                #pragma unroll
                for (int r = 0; r < RPB; ++r) buf[cur ^ 1][r] = row4[r][inx];
            }
        }
        if (k < NITER - 1 || tid < TAILN) {
            const int   i  = tid + k * BLOCK;
            const int   t  = i >> 3;
            const float tF = (float)t;
            const float wt = 1.0f - tF * invT;

            float acc = 0.0f;
            #pragma unroll
            for (int r = 0; r < RPB; ++r) {
                if (j == j0[r]) {      // loop-invariant per thread
                    const int   c  = comp[r];
                    const float4 v = buf[cur][r];
                    const float lp = c == 0 ? v.x : c == 1 ? v.y
                                   : c == 2 ? v.z : v.w;
                    acc -= lp;
                    const float pc  = __expf(lp);
                    const float tlv = fmaxf(tff[r] - tF, 0.0f);
                    earl += pc * wt * (1.0f - tlv * invT);
                }
            }
            s_cls[j][t] = acc;         // unique (j,t) per thread; all written
        }
    }

    // per-row stopping-time quad (line is L2-hot from the stream)
    if (tid < RPB) {
        const int n = n0 + tid;
        const size_t rb = (size_t)n * TT;
        const int lb = yt[rb];
        const int tf = (int)tl[rb];
        const double e   = (double)__expf(logp[rb * CC + (size_t)tf * CC + lb]);
        const double tfd = (double)tf;
        ws[ROW0 + 4 * n + 0] = e;
        ws[ROW0 + 4 * n + 1] = e * tfd;
        ws[ROW0 + 4 * n + 2] = e * tfd * tfd;
        ws[ROW0 + 4 * n + 3] = (double)lb;
    }

    // earliness block partial: f64 wave reduce -> plain store
    double ed = (double)earl;
    for (int off = 32; off > 0; off >>= 1)
        ed += __shfl_down(ed, off, 64);
    if ((tid & 63) == 0) s_red[tid >> 6] = ed;
    __syncthreads();
    if (tid == 0) {
        double s = 0.0;
        #pragma unroll
        for (int w = 0; w < BLOCK / 64; ++w) s += s_red[w];
        ws[E0 + blockIdx.x] = s;
    }

    // cls block partial -> transposed store (contiguous reads in k3)
    if (tid < TT) {
        float s = 0.0f;
        #pragma unroll
        for (int jj = 0; jj < 8; ++jj) s += s_cls[jj][tid];
        ws[(size_t)tid * GRID + blockIdx.x] = (double)s;
    }
}

__global__ __launch_bounds__(512) void stp_scalar(
    double* __restrict__ ws)
{
    __shared__ double sA[CC], sB[CC], sD[CC];
    __shared__ double s_red[8];
    const int tid = threadIdx.x;

    if (tid < CC) { sA[tid] = 0.0; sB[tid] = 0.0; sD[tid] = 0.0; }
    __syncthreads();

    double e = ws[E0 + tid] + ws[E0 + 512 + tid];
    for (int off = 32; off > 0; off >>= 1)
        e += __shfl_down(e, off, 64);
    if ((tid & 63) == 0) s_red[tid >> 6] = e;

    #pragma unroll
    for (int k = 0; k < NN / 512; ++k) {
        const int n = tid + k * 512;
        const double ev = ws[ROW0 + 4 * n + 0];
        const double b  = ws[ROW0 + 4 * n + 1];
        const double d  = ws[ROW0 + 4 * n + 2];
        const int    lb = (int)ws[ROW0 + 4 * n + 3];
        atomicAdd(&sA[lb], ev);
        atomicAdd(&sB[lb], b);
        atomicAdd(&sD[lb], d);
    }
    __syncthreads();

    if (tid == 0) {
        double p = 0.0;
        #pragma unroll
        for (int c = 0; c < CC; ++c)
            p += sA[c] * sD[c] - sB[c] * sB[c];
        p /= (365.0 * 365.0);
        double et = 0.0;
        #pragma unroll
        for (int w = 0; w < 8; ++w) et += s_red[w];
        et /= (double)NN;
        ws[SC] = (1.0 / 3.0) * (et + p);
    }
}

__global__ __launch_bounds__(256) void stp_out(
    const double* __restrict__ ws, float* __restrict__ out)
{
    __shared__ double s_red[4];
    const int t   = blockIdx.x;
    const int tid = threadIdx.x;

    const double* p = ws + (size_t)t * GRID;
    double s = 0.0;
    #pragma unroll
    for (int k = 0; k < GRID / 256; ++k) s += p[tid + k * 256];
    for (int off = 32; off > 0; off >>= 1)
        s += __shfl_down(s, off, 64);
    if ((tid & 63) == 0) s_red[tid >> 6] = s;
    __syncthreads();
    if (tid == 0) {
        double cls = s_red[0] + s_red[1] + s_red[2] + s_red[3];
        out[t] = (float)((1.0 / 3.0) * (cls / (double)NN) - ws[SC]);
    }
}

extern "C" void kernel_launch(void* const* d_in, const int* in_sizes, int n_in,
                              void* d_out, int out_size, void* d_ws, size_t ws_size,
                              hipStream_t stream)
{
    const float* logp = (const float*)d_in[0];
    const float* tl   = (const float*)d_in[1];
    const int*   yt   = (const int*)d_in[2];
    float* out = (float*)d_out;
    double* ws = (double*)d_ws;

    stp_main<<<GRID, BLOCK, 0, stream>>>(logp, tl, yt, ws);
    stp_scalar<<<1, 512, 0, stream>>>(ws);
    stp_out<<<TT, 256, 0, stream>>>(ws, out);
}

// Round 9
// 44.414 us; speedup vs baseline: 4.4069x; 1.0018x over previous
//
#include <hip/hip_runtime.h>

#define NN 4096
#define TT 365
#define CC 32
#define RPB 4                      // rows per block
#define BLOCK 512                  // 8 waves
#define GRID (NN / RPB)            // 1024 blocks -> 32 waves/CU (8/SIMD)
#define F4_PER_ROW (TT * CC / 4)   // 2920
#define KFULL 5                    // full 512-wide batches per row
#define KTAIL 360                  // 2920 - 5*512
#define LDS_PAD 369

// ws layout (doubles), every location plain-stored each call (no memset):
// [0 .. TT*GRID)       cls partials TRANSPOSED: ws[t*GRID + b]
// [E0 .. E0+GRID)      per-block earliness partials
// [ROW0 .. ROW0+4*NN)  per-row quads: e, e*tf, e*tf^2, (double)label
// [SC]                 scalar (written by k2, read by k3)
#define E0   (TT * GRID)
#define ROW0 (E0 + GRID)
#define SC   (ROW0 + 4 * NN)

__global__ __launch_bounds__(BLOCK, 8) void stp_main(
    const float* __restrict__ logp,   // (N,T,C)
    const float* __restrict__ tl,     // (N,T) -- only column 0 read
    const int*  __restrict__ yt,      // (N,T) -- only column 0 read
    double* __restrict__ ws)
{
    __shared__ float  s_cls[8][LDS_PAD];   // [chunk j][t]; bijective stores
    __shared__ double s_red[BLOCK / 64];

    const int tid = threadIdx.x;
    const int n0  = blockIdx.x * RPB;

    int   lab[RPB], j0[RPB], comp[RPB];
    float tff[RPB];
    const float4* row4[RPB];
    #pragma unroll
    for (int r = 0; r < RPB; ++r) {
        const size_t rb = (size_t)(n0 + r) * TT;
        lab[r]  = yt[rb];              // block-uniform
        tff[r]  = tl[rb];              // tl[n,0] = lengths-1 = t_final (exact)
        j0[r]   = lab[r] >> 2;
        comp[r] = lab[r] & 3;
        row4[r] = (const float4*)(logp + rb * CC);
    }

    const int j = tid & 7;             // fixed chunk index per thread
    float acc[KFULL + 1] = {0.f, 0.f, 0.f, 0.f, 0.f, 0.f};
    float earl = 0.0f;
    const float invT = 1.0f / 365.0f;

    // ---- rows processed SEQUENTIALLY in address order (fewer, fatter
    //      DRAM streams: 1024 device-wide, 8 KB contiguous per step) ----
    for (int r = 0; r < RPB; ++r) {
        const float4* rp = row4[r];

        float4 v[KFULL + 1];
        #pragma unroll
        for (int k = 0; k <= KFULL; ++k)
            if (k < KFULL || tid < KTAIL) v[k] = rp[tid + k * BLOCK];

        if (j == j0[r]) {              // per-lane ownership (8/64 lanes)
            const int c = comp[r];
            #pragma unroll
            for (int k = 0; k <= KFULL; ++k) {
                if (k < KFULL || tid < KTAIL) {
                    const int   t  = (tid >> 3) + 64 * k;
                    const float tF = (float)t;
                    const float lp = c == 0 ? v[k].x : c == 1 ? v[k].y
                                   : c == 2 ? v[k].z : v[k].w;
                    acc[k] -= lp;
                    const float pc  = __expf(lp);
                    const float tlv = fmaxf(tff[r] - tF, 0.0f);
                    earl += pc * (1.0f - tF * invT) * (1.0f - tlv * invT);
                }
            }
        }
    }

    // single LDS store pass: bijective (j, t) coverage, no init needed
    #pragma unroll
    for (int k = 0; k <= KFULL; ++k)
        if (k < KFULL || tid < KTAIL)
            s_cls[j][(tid >> 3) + 64 * k] = acc[k];

    // per-row stopping-time quad (line is cache-hot from the stream)
    if (tid < RPB) {
        const int n = n0 + tid;
        const size_t rb = (size_t)n * TT;
        const int lb = yt[rb];
        const int tf = (int)tl[rb];
        const double e   = (double)__expf(logp[rb * CC + (size_t)tf * CC + lb]);
        const double tfd = (double)tf;
        ws[ROW0 + 4 * n + 0] = e;
        ws[ROW0 + 4 * n + 1] = e * tfd;
        ws[ROW0 + 4 * n + 2] = e * tfd * tfd;
        ws[ROW0 + 4 * n + 3] = (double)lb;
    }

    // earliness block partial: f64 wave reduce -> plain store
    double ed = (double)earl;
    for (int off = 32; off > 0; off >>= 1)
        ed += __shfl_down(ed, off, 64);
    if ((tid & 63) == 0) s_red[tid >> 6] = ed;
    __syncthreads();
    if (tid == 0) {
        double s = 0.0;
        #pragma unroll
        for (int w = 0; w < BLOCK / 64; ++w) s += s_red[w];
        ws[E0 + blockIdx.x] = s;
    }

    // cls block partial -> transposed store (contiguous reads in k3)
    if (tid < TT) {
        float s = 0.0f;
        #pragma unroll
        for (int jj = 0; jj < 8; ++jj) s += s_cls[jj][tid];
        ws[(size_t)tid * GRID + blockIdx.x] = (double)s;
    }
}

__global__ __launch_bounds__(512) void stp_scalar(
    double* __restrict__ ws)
{
    __shared__ double sA[CC], sB[CC], sD[CC];
    __shared__ double s_red[8];
    const int tid = threadIdx.x;

    if (tid < CC) { sA[tid] = 0.0; sB[tid] = 0.0; sD[tid] = 0.0; }
    __syncthreads();

    double e = ws[E0 + tid] + ws[E0 + 512 + tid];
    for (int off = 32; off > 0; off >>= 1)
        e += __shfl_down(e, off, 64);
    if ((tid & 63) == 0) s_red[tid >> 6] = e;

    #pragma unroll
    for (int k = 0; k < NN / 512; ++k) {
        const int n = tid + k * 512;
        const double ev = ws[ROW0 + 4 * n + 0];
        const double b  = ws[ROW0 + 4 * n + 1];
        const double d  = ws[ROW0 + 4 * n + 2];
        const int    lb = (int)ws[ROW0 + 4 * n + 3];
        atomicAdd(&sA[lb], ev);
        atomicAdd(&sB[lb], b);
        atomicAdd(&sD[lb], d);
    }
    __syncthreads();

    if (tid == 0) {
        double p = 0.0;
        #pragma unroll
        for (int c = 0; c < CC; ++c)
            p += sA[c] * sD[c] - sB[c] * sB[c];
        p /= (365.0 * 365.0);
        double et = 0.0;
        #pragma unroll
        for (int w = 0; w < 8; ++w) et += s_red[w];
        et /= (double)NN;
        ws[SC] = (1.0 / 3.0) * (et + p);
    }
}

__global__ __launch_bounds__(256) void stp_out(
    const double* __restrict__ ws, float* __restrict__ out)
{
    __shared__ double s_red[4];
    const int t   = blockIdx.x;
    const int tid = threadIdx.x;

    const double* p = ws + (size_t)t * GRID;
    double s = 0.0;
    #pragma unroll
    for (int k = 0; k < GRID / 256; ++k) s += p[tid + k * 256];
    for (int off = 32; off > 0; off >>= 1)
        s += __shfl_down(s, off, 64);
    if ((tid & 63) == 0) s_red[tid >> 6] = s;
    __syncthreads();
    if (tid == 0) {
        double cls = s_red[0] + s_red[1] + s_red[2] + s_red[3];
        out[t] = (float)((1.0 / 3.0) * (cls / (double)NN) - ws[SC]);
    }
}

extern "C" void kernel_launch(void* const* d_in, const int* in_sizes, int n_in,
                              void* d_out, int out_size, void* d_ws, size_t ws_size,
                              hipStream_t stream)
{
    const float* logp = (const float*)d_in[0];
    const float* tl   = (const float*)d_in[1];
    const int*   yt   = (const int*)d_in[2];
    float* out = (float*)d_out;
    double* ws = (double*)d_ws;

    stp_main<<<GRID, BLOCK, 0, stream>>>(logp, tl, yt, ws);
    stp_scalar<<<1, 512, 0, stream>>>(ws);
    stp_out<<<TT, 256, 0, stream>>>(ws, out);
}